// Round 10
// baseline (366.696 us; speedup 1.0000x reference)
//
#include <hip/hip_runtime.h>
#include <math.h>

#define GRAPHS 100
#define HIDC 64
#define OUTC 16
#define SLOPE 0.2f
#define BSHIFT 8
#define MAXNB 512
#define BKT_CAP 10240
#define SCAT_BLOCKS 512

typedef unsigned short ushort_t;
typedef short bf16x8 __attribute__((ext_vector_type(8)));
typedef float f32x4 __attribute__((ext_vector_type(4)));
typedef float f32x2 __attribute__((ext_vector_type(2)));
typedef ushort_t u16x8 __attribute__((ext_vector_type(8)));
typedef ushort_t u16x4 __attribute__((ext_vector_type(4)));

__device__ __forceinline__ float lrelu(float v) { return v > 0.f ? v : SLOPE * v; }
__device__ __forceinline__ void atomAddG(float* p, float v) { unsafeAtomicAdd(p, v); }
__device__ __forceinline__ float bf2f(ushort_t u) {
    unsigned int x = ((unsigned int)u) << 16;
    return __builtin_bit_cast(float, x);
}
__device__ __forceinline__ ushort_t f2bf(float f) {
    unsigned int u = __builtin_bit_cast(unsigned int, f);
    u += 0x7FFFu + ((u >> 16) & 1u);  // RNE
    return (ushort_t)(u >> 16);
}
__device__ __forceinline__ unsigned int pack2(float lo, float hi) {
    return (unsigned int)f2bf(lo) | ((unsigned int)f2bf(hi) << 16);
}
// MAC of 2 bf16 feats (one u32) scaled by w into f32x2 acc -> v_pk_fma_f32
__device__ __forceinline__ void mac2(unsigned int u, float w, f32x2& a) {
    f32x2 hv;
    hv.x = __builtin_bit_cast(float, u << 16);
    hv.y = __builtin_bit_cast(float, u & 0xFFFF0000u);
    f32x2 w2 = {w, w};
    a = __builtin_elementwise_fma(hv, w2, a);
}

// ------- MFMA bf16 GEMM + fused alpha epilogue (device body) -------
template <bool A_IS_BF16, int ASTRIDE>
__device__ __forceinline__ void gemm_alpha_body(
    const void* __restrict__ Av, const float* __restrict__ W, ushort_t* __restrict__ Cbf,
    const float* __restrict__ att_src, const float* __restrict__ att_dst,
    float* __restrict__ asrc, float* __restrict__ adst, int M, int K, int N,
    int row0, int head, ushort_t* As, ushort_t* Bs, float (*ps)[64], float (*pd)[64]) {
    const int tid = threadIdx.x;
    const int col0 = head * 64;
    const int lane = tid & 63;
    const int wv = tid >> 6;
    const int wr = (wv >> 1) * 32, wc = (wv & 1) * 32;
    const int l15 = lane & 15, l4 = lane >> 4;
    const int srow = tid >> 2;
    const int skoff = (tid & 3) * 8;
    const int bc = tid & 63, bk = (tid >> 6) * 8;

    f32x4 acc[2][2] = {};

    for (int k0 = 0; k0 < K; k0 += 32) {
        {
            int gr = row0 + srow;
            uint4 v = {0u, 0u, 0u, 0u};
            if (gr < M) {
                if (A_IS_BF16) {
                    const ushort_t* Ab = (const ushort_t*)Av;
                    v = *(const uint4*)(Ab + (size_t)gr * K + k0 + skoff);
                } else {
                    const float* Af = (const float*)Av;
                    const float4 a0 = *(const float4*)(Af + (size_t)gr * K + k0 + skoff);
                    const float4 a1 = *(const float4*)(Af + (size_t)gr * K + k0 + skoff + 4);
                    v.x = pack2(a0.x, a0.y);
                    v.y = pack2(a0.z, a0.w);
                    v.z = pack2(a1.x, a1.y);
                    v.w = pack2(a1.z, a1.w);
                }
            }
            *(uint4*)&As[srow * 40 + skoff] = v;
        }
        {
#pragma unroll
            for (int j = 0; j < 8; ++j) {
                float w = W[(size_t)(k0 + bk + j) * N + col0 + bc];
                Bs[bc * 40 + bk + j] = f2bf(w);
            }
        }
        __syncthreads();
        bf16x8 af[2], bfr[2];
#pragma unroll
        for (int mi = 0; mi < 2; ++mi)
            af[mi] = *(const bf16x8*)&As[(wr + mi * 16 + l15) * 40 + l4 * 8];
#pragma unroll
        for (int ni = 0; ni < 2; ++ni)
            bfr[ni] = *(const bf16x8*)&Bs[(wc + ni * 16 + l15) * 40 + l4 * 8];
#pragma unroll
        for (int mi = 0; mi < 2; ++mi)
#pragma unroll
            for (int ni = 0; ni < 2; ++ni)
                acc[mi][ni] = __builtin_amdgcn_mfma_f32_16x16x32_bf16(af[mi], bfr[ni],
                                                                     acc[mi][ni], 0, 0, 0);
        __syncthreads();
    }
    // C write: D row = (lane>>4)*4 + r, col = lane&15
#pragma unroll
    for (int mi = 0; mi < 2; ++mi)
#pragma unroll
        for (int ni = 0; ni < 2; ++ni)
#pragma unroll
            for (int r = 0; r < 4; ++r) {
                int row = row0 + wr + mi * 16 + l4 * 4 + r;
                int colg = col0 + wc + ni * 16 + l15;
                if (row < M) Cbf[(size_t)row * N + colg] = f2bf(acc[mi][ni][r]);
            }
    // alpha epilogue
    float as_c[2], ad_c[2];
#pragma unroll
    for (int ni = 0; ni < 2; ++ni) {
        int cidx = col0 + wc + ni * 16 + l15;
        as_c[ni] = att_src[cidx];
        ad_c[ni] = att_dst[cidx];
    }
#pragma unroll
    for (int mi = 0; mi < 2; ++mi)
#pragma unroll
        for (int r = 0; r < 4; ++r) {
            float s = acc[mi][0][r] * as_c[0] + acc[mi][1][r] * as_c[1];
            float d = acc[mi][0][r] * ad_c[0] + acc[mi][1][r] * ad_c[1];
#pragma unroll
            for (int off = 1; off < 16; off <<= 1) {
                s += __shfl_xor(s, off);
                d += __shfl_xor(d, off);
            }
            if (l15 == 0) {
                int rl = wr + mi * 16 + l4 * 4 + r;
                ps[wc >> 5][rl] = s;
                pd[wc >> 5][rl] = d;
            }
        }
    __syncthreads();
    if (tid < 64) {
        int row = row0 + tid;
        if (row < M) {
            asrc[ASTRIDE * row + head] = ps[0][tid] + ps[1][tid];
            adst[ASTRIDE * row + head] = pd[0][tid] + pd[1][tid];
        }
    }
}

template <bool A_IS_BF16, int ASTRIDE>
__global__ __launch_bounds__(256) void mfma_gemm_alpha(const void* __restrict__ Av,
                                                       const float* __restrict__ W,
                                                       ushort_t* __restrict__ Cbf,
                                                       const float* __restrict__ att_src,
                                                       const float* __restrict__ att_dst,
                                                       float* __restrict__ asrc,
                                                       float* __restrict__ adst,
                                                       int M, int K, int N) {
    __shared__ ushort_t As[64 * 40];
    __shared__ ushort_t Bs[64 * 40];
    __shared__ float ps[2][64], pd[2][64];
    gemm_alpha_body<A_IS_BF16, ASTRIDE>(Av, W, Cbf, att_src, att_dst, asrc, adst, M, K, N,
                                        blockIdx.x * 64, blockIdx.y, As, Bs, ps, pd);
}

// ---------------- bucket-sort CSR build ----------------
__global__ __launch_bounds__(256) void bucket_hist(const int* __restrict__ ei, int E,
                                                   int* __restrict__ bcnt, int NB) {
    __shared__ int h[MAXNB];
    for (int t = threadIdx.x; t < NB; t += 256) h[t] = 0;
    __syncthreads();
    int chunk = (E + gridDim.x - 1) / gridDim.x;
    int e0 = blockIdx.x * chunk;
    int e1 = e0 + chunk < E ? e0 + chunk : E;
    for (int e = e0 + threadIdx.x; e < e1; e += 256)
        atomicAdd(&h[ei[E + e] >> BSHIFT], 1);
    __syncthreads();
    for (int t = threadIdx.x; t < NB; t += 256)
        if (h[t]) atomicAdd(&bcnt[t], h[t]);
}

// scan bucket counts -> bases + cursors; also zero pool accumulators (single block)
__global__ __launch_bounds__(512) void bucket_scan(const int* __restrict__ bcnt,
                                                   int* __restrict__ bbase,
                                                   int* __restrict__ bcursor,
                                                   int* __restrict__ rowptr,
                                                   float* __restrict__ sums,
                                                   float* __restrict__ cnt,
                                                   int NB, int n, int E) {
    __shared__ int sh[512];
    int t = threadIdx.x;
    int v = (t < NB) ? bcnt[t] : 0;
    sh[t] = v;
    __syncthreads();
#pragma unroll
    for (int off = 1; off < 512; off <<= 1) {
        int val = (t >= off) ? sh[t - off] : 0;
        __syncthreads();
        sh[t] += val;
        __syncthreads();
    }
    if (t < NB) {
        int base = sh[t] - v;
        bbase[t] = base;
        bcursor[t] = base;
    }
    if (t == 0) {
        bbase[NB] = E;
        rowptr[n] = E;
    }
    for (int k = t; k < GRAPHS * HIDC; k += 512) sums[k] = 0.f;
    for (int k = t; k < GRAPHS; k += 512) cnt[k] = 0.f;
}

// fused: blocks [0,SCAT_BLOCKS) scatter edges into bucket regions; rest do GEMM1+alpha
__global__ __launch_bounds__(256) void scatter_gemm1(
    const int* __restrict__ ei, int E, int* __restrict__ bcursor,
    unsigned int* __restrict__ ebuf, int NB,
    const float* __restrict__ x, const float* __restrict__ W, ushort_t* __restrict__ h1,
    const float* __restrict__ att_src, const float* __restrict__ att_dst,
    float* __restrict__ asrc, float* __restrict__ adst, int M, int gblk) {
    __shared__ ushort_t As[64 * 40];
    __shared__ ushort_t Bs[64 * 40];
    __shared__ float ps[2][64], pd[2][64];
    __shared__ int hh[MAXNB];
    __shared__ int lbase[MAXNB];
    if ((int)blockIdx.x < SCAT_BLOCKS) {
        for (int t = threadIdx.x; t < NB; t += 256) hh[t] = 0;
        __syncthreads();
        int chunk = (E + SCAT_BLOCKS - 1) / SCAT_BLOCKS;
        int e0 = blockIdx.x * chunk;
        int e1 = e0 + chunk < E ? e0 + chunk : E;
        for (int e = e0 + threadIdx.x; e < e1; e += 256)
            atomicAdd(&hh[ei[E + e] >> BSHIFT], 1);
        __syncthreads();
        for (int t = threadIdx.x; t < NB; t += 256) {
            int c = hh[t];
            lbase[t] = c ? atomicAdd(&bcursor[t], c) : 0;
            hh[t] = 0;  // reuse as running cursor
        }
        __syncthreads();
        for (int e = e0 + threadIdx.x; e < e1; e += 256) {
            int d = ei[E + e];
            int s = ei[e];
            int b = d >> BSHIFT;
            int off = atomicAdd(&hh[b], 1);
            ebuf[lbase[b] + off] = (unsigned)s | ((unsigned)(d & ((1 << BSHIFT) - 1)) << 24);
        }
    } else {
        int bid = blockIdx.x - SCAT_BLOCKS;
        int head = bid / gblk;
        int row0 = (bid - head * gblk) * 64;
        gemm_alpha_body<false, 2>(x, W, h1, att_src, att_dst, asrc, adst, M, 128, 128,
                                  row0, head, As, Bs, ps, pd);
    }
}

__global__ __launch_bounds__(256) void bucket_build(const unsigned int* __restrict__ ebuf,
                                                    const int* __restrict__ bbase,
                                                    int* __restrict__ rowptr,
                                                    int* __restrict__ col, int n) {
    __shared__ int hist[256];
    __shared__ int curs[256];
    __shared__ int sh[256];
    __shared__ int lsrc[BKT_CAP];
    int b = blockIdx.x;
    int e0 = bbase[b], e1 = bbase[b + 1];
    int cnt = e1 - e0;
    int t = threadIdx.x;
    hist[t] = 0;
    __syncthreads();
    for (int k = t; k < cnt; k += 256) atomicAdd(&hist[ebuf[e0 + k] >> 24], 1);
    __syncthreads();
    int v = hist[t];
    sh[t] = v;
    __syncthreads();
#pragma unroll
    for (int off = 1; off < 256; off <<= 1) {
        int val = (t >= off) ? sh[t - off] : 0;
        __syncthreads();
        sh[t] += val;
        __syncthreads();
    }
    int ex = sh[t] - v;
    curs[t] = ex;
    int node = (b << BSHIFT) + t;
    if (node < n) rowptr[node] = e0 + ex;
    __syncthreads();
    for (int k = t; k < cnt; k += 256) {
        unsigned pk = ebuf[e0 + k];
        int ld = pk >> 24;
        int off = atomicAdd(&curs[ld], 1);
        if (off < BKT_CAP) lsrc[off] = (int)(pk & 0xFFFFFFu);
    }
    __syncthreads();
    int lim = cnt < BKT_CAP ? cnt : BKT_CAP;
    for (int k = t; k < lim; k += 256) col[e0 + k] = lsrc[k];
}

// ---------------- fused GAT aggregation: 16-lane groups, 16 edges in flight ----------------
// layer1: h [n,128] bf16; out = relu(agg/den + b1) bf16. 32-bit offsets, pk-fma MAC.
__global__ __launch_bounds__(256) void gat_agg1(const int* __restrict__ rowptr,
                                                const int* __restrict__ col,
                                                const ushort_t* __restrict__ h,
                                                const float* __restrict__ asrc,
                                                const float* __restrict__ adst,
                                                const float* __restrict__ b1,
                                                ushort_t* __restrict__ outb, int n) {
    int i = (blockIdx.x * blockDim.x + threadIdx.x) >> 6;
    if (i >= n) return;
    int lane = threadIdx.x & 63;
    int grp = lane >> 4, c = lane & 15;  // feats 8c..8c+7, head = c>>3
    int head = c >> 3;
    const char* hb = (const char*)h;
    const char* ab = (const char*)asrc;
    float ad = adst[2 * i + head];
    f32x2 acc2[4] = {};
    float den = 0.f;
    unsigned coff = (unsigned)c << 4;
    if (grp == 0) {  // self-loop
        float w = __expf(lrelu(asrc[2 * i + head] + ad));
        uint4 hq = *(const uint4*)(hb + (((unsigned)i << 8) + coff));
        mac2(hq.x, w, acc2[0]);
        mac2(hq.y, w, acc2[1]);
        mac2(hq.z, w, acc2[2]);
        mac2(hq.w, w, acc2[3]);
        den = w;
    }
    int e0 = rowptr[i], end = rowptr[i + 1];
    unsigned aoff = ((unsigned)head << 2);
    for (int e = e0; e < end; e += 16) {
        float wv[4];
        uint4 hq[4];
#pragma unroll
        for (int q = 0; q < 4; ++q) {
            int idx = e + 4 * q + grp;
            bool vld = idx < end;
            int s = col[vld ? idx : e0];
            float as = *(const float*)(ab + (((unsigned)s << 3) + aoff));
            hq[q] = *(const uint4*)(hb + (((unsigned)s << 8) + coff));
            wv[q] = vld ? __expf(lrelu(as + ad)) : 0.f;
        }
#pragma unroll
        for (int q = 0; q < 4; ++q) {
            mac2(hq[q].x, wv[q], acc2[0]);
            mac2(hq[q].y, wv[q], acc2[1]);
            mac2(hq[q].z, wv[q], acc2[2]);
            mac2(hq[q].w, wv[q], acc2[3]);
            den += wv[q];
        }
    }
#pragma unroll
    for (int k = 0; k < 4; ++k) {
        acc2[k].x += __shfl_xor(acc2[k].x, 16);
        acc2[k].x += __shfl_xor(acc2[k].x, 32);
        acc2[k].y += __shfl_xor(acc2[k].y, 16);
        acc2[k].y += __shfl_xor(acc2[k].y, 32);
    }
    den += __shfl_xor(den, 16);
    den += __shfl_xor(den, 32);
    if (grp == 0) {
        float inv = 1.f / den;
        u16x8 ov;
#pragma unroll
        for (int k = 0; k < 4; ++k) {
            float r0 = fmaf(acc2[k].x, inv, b1[8 * c + 2 * k]);
            float r1 = fmaf(acc2[k].y, inv, b1[8 * c + 2 * k + 1]);
            r0 = r0 > 0.f ? r0 : 0.f;
            r1 = r1 > 0.f ? r1 : 0.f;
            ov[2 * k] = f2bf(r0);
            ov[2 * k + 1] = f2bf(r1);
        }
        *((u16x8*)outb + (size_t)i * 16 + c) = ov;
    }
}

// layer2: h [n,64] bf16, 1 head; out bf16 [n,64]
__global__ __launch_bounds__(256) void gat_agg2(const int* __restrict__ rowptr,
                                                const int* __restrict__ col,
                                                const ushort_t* __restrict__ h,
                                                const float* __restrict__ asrc,
                                                const float* __restrict__ adst,
                                                ushort_t* __restrict__ outb, int n) {
    int i = (blockIdx.x * blockDim.x + threadIdx.x) >> 6;
    if (i >= n) return;
    int lane = threadIdx.x & 63;
    int grp = lane >> 4, c = lane & 15;  // feats 4c..4c+3
    const char* hb = (const char*)h;
    const char* ab = (const char*)asrc;
    float ad = adst[i];
    f32x2 acc2[2] = {};
    float den = 0.f;
    unsigned coff = (unsigned)c << 3;
    if (grp == 0) {
        float w = __expf(lrelu(asrc[i] + ad));
        uint2 hq = *(const uint2*)(hb + (((unsigned)i << 7) + coff));
        mac2(hq.x, w, acc2[0]);
        mac2(hq.y, w, acc2[1]);
        den = w;
    }
    int e0 = rowptr[i], end = rowptr[i + 1];
    for (int e = e0; e < end; e += 16) {
        float wv[4];
        uint2 hq[4];
#pragma unroll
        for (int q = 0; q < 4; ++q) {
            int idx = e + 4 * q + grp;
            bool vld = idx < end;
            int s = col[vld ? idx : e0];
            float as = *(const float*)(ab + ((unsigned)s << 2));
            hq[q] = *(const uint2*)(hb + (((unsigned)s << 7) + coff));
            wv[q] = vld ? __expf(lrelu(as + ad)) : 0.f;
        }
#pragma unroll
        for (int q = 0; q < 4; ++q) {
            mac2(hq[q].x, wv[q], acc2[0]);
            mac2(hq[q].y, wv[q], acc2[1]);
            den += wv[q];
        }
    }
#pragma unroll
    for (int k = 0; k < 2; ++k) {
        acc2[k].x += __shfl_xor(acc2[k].x, 16);
        acc2[k].x += __shfl_xor(acc2[k].x, 32);
        acc2[k].y += __shfl_xor(acc2[k].y, 16);
        acc2[k].y += __shfl_xor(acc2[k].y, 32);
    }
    den += __shfl_xor(den, 16);
    den += __shfl_xor(den, 32);
    if (grp == 0) {
        float inv = 1.f / den;
        u16x4 ov = {f2bf(acc2[0].x * inv), f2bf(acc2[0].y * inv), f2bf(acc2[1].x * inv),
                    f2bf(acc2[1].y * inv)};
        *((u16x4*)outb + (size_t)i * 16 + c) = ov;
    }
}

// ---------------- mean pool (batch sorted), bf16 input ----------------
#define NPB 256
__global__ __launch_bounds__(256) void pool_kernel(const ushort_t* __restrict__ h,
                                                   const int* __restrict__ batch,
                                                   float* __restrict__ sums,
                                                   float* __restrict__ cnt, int n) {
    __shared__ float ls[GRAPHS * HIDC];
    __shared__ float lc[GRAPHS];
    int base = blockIdx.x * NPB;
    for (int t = threadIdx.x; t < GRAPHS * HIDC; t += blockDim.x) ls[t] = 0.f;
    for (int t = threadIdx.x; t < GRAPHS; t += blockDim.x) lc[t] = 0.f;
    __syncthreads();
    int wave = threadIdx.x >> 6, lane = threadIdx.x & 63;
    int end = base + NPB < n ? base + NPB : n;
    for (int i = base + wave; i < end; i += 4) {
        int g = batch[i];
        unsafeAtomicAdd(&ls[g * HIDC + lane], bf2f(h[(size_t)i * HIDC + lane]));
        if (lane == 0) unsafeAtomicAdd(&lc[g], 1.f);
    }
    __syncthreads();
    int gmin = batch[base];
    int gmax = batch[end - 1];
    int ng = gmax - gmin + 1;
    for (int t = threadIdx.x; t < ng * HIDC; t += blockDim.x) {
        int g = gmin + t / HIDC, c = t % HIDC;
        atomAddG(&sums[g * HIDC + c], ls[g * HIDC + c]);
    }
    for (int g = gmin + (int)threadIdx.x; g <= gmax; g += blockDim.x)
        atomAddG(&cnt[g], lc[g]);
}

// ---------------- final linear ----------------
__global__ void final_kernel(const float* __restrict__ sums, const float* __restrict__ cnt,
                             const float* __restrict__ b2, const float* __restrict__ Wl,
                             const float* __restrict__ bl, float* __restrict__ out) {
    int t = blockIdx.x * blockDim.x + threadIdx.x;
    if (t < GRAPHS * OUTC) {
        int g = t / OUTC, o = t % OUTC;
        float c = cnt[g];
        c = c > 1.f ? c : 1.f;
        float inv = 1.f / c;
        float acc = bl[o];
        for (int k = 0; k < HIDC; ++k)
            acc += (sums[g * HIDC + k] * inv + b2[k]) * Wl[k * OUTC + o];
        out[t] = acc;
    }
}

extern "C" void kernel_launch(void* const* d_in, const int* in_sizes, int n_in, void* d_out,
                              int out_size, void* d_ws, size_t ws_size, hipStream_t stream) {
    const float* x = (const float*)d_in[0];
    const int* ei = (const int*)d_in[1];
    const int* batch = (const int*)d_in[2];
    const float* W1 = (const float*)d_in[3];
    const float* att_src1 = (const float*)d_in[4];
    const float* att_dst1 = (const float*)d_in[5];
    const float* b1 = (const float*)d_in[6];
    const float* W2 = (const float*)d_in[7];
    const float* att_src2 = (const float*)d_in[8];
    const float* att_dst2 = (const float*)d_in[9];
    const float* b2 = (const float*)d_in[10];
    const float* Wl = (const float*)d_in[11];
    const float* bl = (const float*)d_in[12];
    float* out = (float*)d_out;

    const int n = in_sizes[2];
    const int E = in_sizes[1] / 2;

    char* p = (char*)d_ws;
    auto alloc = [&](size_t bytes) {
        char* r = p;
        p += (bytes + 255) & ~(size_t)255;
        return r;
    };
    ushort_t* h1 = (ushort_t*)alloc((size_t)n * 128 * 2);
    ushort_t* hrelu = (ushort_t*)alloc((size_t)n * 128 * 2);
    ushort_t* h2 = (ushort_t*)alloc((size_t)n * 64 * 2);
    ushort_t* conv2 = (ushort_t*)alloc((size_t)n * 64 * 2);
    float* asrc1 = (float*)alloc((size_t)n * 2 * 4);
    float* adst1 = (float*)alloc((size_t)n * 2 * 4);
    float* asrc2 = (float*)alloc((size_t)n * 4);
    float* adst2 = (float*)alloc((size_t)n * 4);
    float* sums = (float*)alloc(GRAPHS * HIDC * 4);
    float* cnt = (float*)alloc(GRAPHS * 4);
    int* bcnt = (int*)alloc(MAXNB * 4);
    int* bbase = (int*)alloc((MAXNB + 1) * 4);
    int* bcursor = (int*)alloc(MAXNB * 4);
    int* rowptr = (int*)alloc(((size_t)n + 1) * 4);
    unsigned int* ebuf = (unsigned int*)alloc((size_t)E * 4);
    int* col = (int*)alloc((size_t)E * 4);

    const int NB = (n + 255) >> BSHIFT;
    const int gblk = (n + 63) / 64;

    // ---- CSR build (hist/scan), then scatter fused with GEMM1 ----
    hipMemsetAsync(bcnt, 0, NB * sizeof(int), stream);
    bucket_hist<<<SCAT_BLOCKS, 256, 0, stream>>>(ei, E, bcnt, NB);
    bucket_scan<<<1, 512, 0, stream>>>(bcnt, bbase, bcursor, rowptr, sums, cnt, NB, n, E);
    scatter_gemm1<<<SCAT_BLOCKS + 2 * gblk, 256, 0, stream>>>(
        ei, E, bcursor, ebuf, NB, x, W1, h1, att_src1, att_dst1, asrc1, adst1, n, gblk);
    bucket_build<<<NB, 256, 0, stream>>>(ebuf, bbase, rowptr, col, n);

    // ---- layer 1 aggregation ----
    gat_agg1<<<(n + 3) / 4, 256, 0, stream>>>(rowptr, col, h1, asrc1, adst1, b1, hrelu, n);

    // ---- layer 2 ----
    mfma_gemm_alpha<true, 1><<<dim3(gblk, 1), 256, 0, stream>>>(
        hrelu, W2, h2, att_src2, att_dst2, asrc2, adst2, n, 128, 64);
    gat_agg2<<<(n + 3) / 4, 256, 0, stream>>>(rowptr, col, h2, asrc2, adst2, conv2, n);

    // ---- pool + final (b2 folded into final) ----
    pool_kernel<<<(n + NPB - 1) / NPB, 256, 0, stream>>>(conv2, batch, sums, cnt, n);
    final_kernel<<<(GRAPHS * OUTC + 255) / 256, 256, 0, stream>>>(sums, cnt, b2, Wl, bl, out);
}